// Round 1
// baseline (460.178 us; speedup 1.0000x reference)
//
#include <hip/hip_runtime.h>

// Stage2GNN: encoder (2x K=64 GEMM) -> GAT conv1 -> GAT conv2 -> fc1 -> fc2
// All fp32 vector compute (no fp32 MFMA on CDNA4). CSR-by-dst built on device
// each call (atomic region assignment; segment order irrelevant).
//
// Workspace usage: ~44.5 MB (hA/hB 20.48MB each + CSR/attention scratch).

#define N_NODES 40000
#define N_EDGES 640000
#define ETOT    (N_NODES + N_EDGES)
#define DIM     128

enum { EPI_RELU = 0, EPI_ADDHALF = 1, EPI_STORE = 2, EPI_BIAS = 3 };

__device__ __forceinline__ float wave_reduce_max(float v) {
#pragma unroll
    for (int off = 32; off; off >>= 1) v = fmaxf(v, __shfl_xor(v, off));
    return v;
}
__device__ __forceinline__ float wave_reduce_sum(float v) {
#pragma unroll
    for (int off = 32; off; off >>= 1) v += __shfl_xor(v, off);
    return v;
}
__device__ __forceinline__ float dot4acc(float4 a, float4 w, float acc) {
    acc = fmaf(a.x, w.x, acc);
    acc = fmaf(a.y, w.y, acc);
    acc = fmaf(a.z, w.z, acc);
    acc = fmaf(a.w, w.w, acc);
    return acc;
}

// ---------------- CSR build ----------------
__global__ void k_deg_init(int* __restrict__ deg, int* __restrict__ counter) {
    int i = blockIdx.x * 256 + threadIdx.x;
    if (i < N_NODES) deg[i] = 1;  // self loop
    if (i == 0) *counter = 0;
}

__global__ void k_deg_count(const int* __restrict__ dst, int* __restrict__ deg) {
    int t = blockIdx.x * 256 + threadIdx.x;
    if (t < N_EDGES) atomicAdd(&deg[dst[t]], 1);
}

// Assign each node a contiguous region of size deg[i] (order irrelevant).
__global__ void k_assign(const int* __restrict__ deg, int* __restrict__ counter,
                         int* __restrict__ start, int* __restrict__ cursor,
                         int* __restrict__ csr_src) {
    int i = blockIdx.x * 256 + threadIdx.x;
    if (i >= N_NODES) return;
    int d = deg[i];
    int s = atomicAdd(counter, d);
    start[i]  = s;
    csr_src[s] = i;      // self loop occupies first slot
    cursor[i] = s + 1;
}

__global__ void k_fill_edges(const int* __restrict__ src, const int* __restrict__ dst,
                             int* __restrict__ cursor, int* __restrict__ csr_src) {
    int t = blockIdx.x * 256 + threadIdx.x;
    if (t < N_EDGES) {
        int p = atomicAdd(&cursor[dst[t]], 1);
        csr_src[p] = src[t];
    }
}

// ---------------- GEMM: out[r][c] = epi( sum_k in[r][col_off+k] * W[c][k] ) ----------------
// block 256 threads; BM=64 rows; thread tile 4 rows x 8 cols; W staged in LDS
// with a bank swizzle (rotate k by 4*((c>>3)&7)) so the 8-col-strided
// ds_read_b128 pattern is <=2-way conflicting instead of 16-way.
template<int K, int EPI>
__global__ __launch_bounds__(256) void k_gemm(
    const float* __restrict__ in, int col_off,
    const float* __restrict__ W, const float* __restrict__ bias,
    float* __restrict__ out, int C, int out_stride)
{
    __shared__ float Ws[128 * K];
    const int tid = threadIdx.x;

    for (int idx = tid * 4; idx < C * K; idx += 1024) {
        float4 w = *(const float4*)&W[idx];
        int c = idx / K;           // K is power of 2 -> shift
        int k = idx & (K - 1);
        int ks = (k + ((c >> 3) & 7) * 4) & (K - 1);
        *(float4*)&Ws[c * K + ks] = w;
    }
    __syncthreads();

    const int rowgrp = tid >> 4;   // 0..15
    const int colgrp = tid & 15;   // 0..15 : 16 lanes share the same x rows (broadcast dedup)
    const int r0 = blockIdx.x * 64 + rowgrp * 4;
    const int c0 = colgrp * 8;

    const float* xp = in + (size_t)r0 * DIM + col_off;

    float acc[4][8];
#pragma unroll
    for (int i = 0; i < 4; ++i)
#pragma unroll
        for (int j = 0; j < 8; ++j) acc[i][j] = 0.f;

#pragma unroll 4
    for (int k0 = 0; k0 < K; k0 += 4) {
        float4 a0 = *(const float4*)(xp + 0 * DIM + k0);
        float4 a1 = *(const float4*)(xp + 1 * DIM + k0);
        float4 a2 = *(const float4*)(xp + 2 * DIM + k0);
        float4 a3 = *(const float4*)(xp + 3 * DIM + k0);
#pragma unroll
        for (int cc = 0; cc < 8; ++cc) {
            int c = c0 + cc;
            int ks = (k0 + ((c >> 3) & 7) * 4) & (K - 1);
            float4 w = *(const float4*)&Ws[c * K + ks];
            acc[0][cc] = dot4acc(a0, w, acc[0][cc]);
            acc[1][cc] = dot4acc(a1, w, acc[1][cc]);
            acc[2][cc] = dot4acc(a2, w, acc[2][cc]);
            acc[3][cc] = dot4acc(a3, w, acc[3][cc]);
        }
    }

#pragma unroll
    for (int rr = 0; rr < 4; ++rr) {
        int r = r0 + rr;
        float* orow = out + (size_t)r * out_stride;
#pragma unroll
        for (int cc = 0; cc < 8; ++cc) {
            int c = c0 + cc;
            if (c < C) {
                float v = acc[rr][cc];
                if constexpr (EPI == EPI_RELU) {
                    orow[c] = fmaxf(v + bias[c], 0.f);
                } else if constexpr (EPI == EPI_ADDHALF) {
                    orow[c] += 0.5f * fmaxf(v + bias[c], 0.f);
                } else if constexpr (EPI == EPI_STORE) {
                    orow[c] = v;
                } else {  // EPI_BIAS
                    orow[c] = v + bias[c];
                }
            }
        }
    }
}

// ---------------- per-node attention logits ----------------
__global__ __launch_bounds__(256) void k_alpha(
    const float* __restrict__ h, const float* __restrict__ a_src,
    const float* __restrict__ a_dst, float* __restrict__ as_, float* __restrict__ ad_)
{
    int wid  = (blockIdx.x * 256 + threadIdx.x) >> 6;
    int lane = threadIdx.x & 63;
    if (wid >= N_NODES) return;
    const float* hr = h + (size_t)wid * DIM;
    float h0 = hr[lane], h1 = hr[lane + 64];
    float s = h0 * a_src[lane] + h1 * a_src[lane + 64];
    float d = h0 * a_dst[lane] + h1 * a_dst[lane + 64];
    s = wave_reduce_sum(s);
    d = wave_reduce_sum(d);
    if (lane == 0) { as_[wid] = s; ad_[wid] = d; }
}

// ---------------- wave-per-node softmax + aggregation ----------------
// out[i] = relu( (sum_j p_j * h[j]) / (sum_j p_j + 1e-16) + bias ),
// p_j = exp(leaky(as[j]+ad[i]) - max). Identical to reference softmax.
__global__ __launch_bounds__(256) void k_aggregate(
    const float* __restrict__ h, const float* __restrict__ as_,
    const float* __restrict__ ad_, const int* __restrict__ start,
    const int* __restrict__ deg, const int* __restrict__ csr_src,
    const float* __restrict__ bias, float* __restrict__ out)
{
    int wid  = (blockIdx.x * 256 + threadIdx.x) >> 6;
    int lane = threadIdx.x & 63;
    if (wid >= N_NODES) return;

    const int s0 = start[wid];
    const int s1 = s0 + deg[wid];
    const float adi = ad_[wid];

    // pass 1: segment max
    float m = -1e30f;
    for (int base = s0; base < s1; base += 64) {
        int k = base + lane;
        if (k < s1) {
            float e = as_[csr_src[k]] + adi;
            e = (e > 0.f) ? e : 0.2f * e;
            m = fmaxf(m, e);
        }
    }
    m = wave_reduce_max(m);

    // pass 2: unnormalized weighted accumulate + weight sum
    float2 acc = make_float2(0.f, 0.f);
    float ssum = 0.f;
    for (int base = s0; base < s1; base += 64) {
        int k = base + lane;
        int cnt = min(64, s1 - base);   // wave-uniform
        int jj = 0;
        float p = 0.f;
        if (k < s1) {
            jj = csr_src[k];
            float e = as_[jj] + adi;
            e = (e > 0.f) ? e : 0.2f * e;
            p = expf(e - m);
            ssum += p;
        }
        for (int t = 0; t < cnt; ++t) {
            float pt = __uint_as_float(__builtin_amdgcn_readlane(__float_as_uint(p), t));
            int   jt = __builtin_amdgcn_readlane(jj, t);
            float2 hv = *(const float2*)&h[(size_t)jt * DIM + 2 * lane];
            acc.x = fmaf(pt, hv.x, acc.x);
            acc.y = fmaf(pt, hv.y, acc.y);
        }
    }
    ssum = wave_reduce_sum(ssum);
    float inv = 1.f / (ssum + 1e-16f);

    float2 b = *(const float2*)&bias[2 * lane];
    float ox = fmaxf(fmaf(acc.x, inv, b.x), 0.f);
    float oy = fmaxf(fmaf(acc.y, inv, b.y), 0.f);
    *(float2*)&out[(size_t)wid * DIM + 2 * lane] = make_float2(ox, oy);
}

extern "C" void kernel_launch(void* const* d_in, const int* in_sizes, int n_in,
                              void* d_out, int out_size, void* d_ws, size_t ws_size,
                              hipStream_t stream) {
    (void)in_sizes; (void)n_in; (void)out_size; (void)ws_size;

    const float* x       = (const float*)d_in[0];
    const int*   ei      = (const int*)d_in[1];
    const float* sat_W   = (const float*)d_in[2];
    const float* sat_b   = (const float*)d_in[3];
    const float* neigh_W = (const float*)d_in[4];
    const float* neigh_b = (const float*)d_in[5];
    const float* c1_W    = (const float*)d_in[6];
    const float* c1_as   = (const float*)d_in[7];
    const float* c1_ad   = (const float*)d_in[8];
    const float* c1_b    = (const float*)d_in[9];
    const float* c2_W    = (const float*)d_in[10];
    const float* c2_as   = (const float*)d_in[11];
    const float* c2_ad   = (const float*)d_in[12];
    const float* c2_b    = (const float*)d_in[13];
    const float* fc1_W   = (const float*)d_in[14];
    const float* fc1_b   = (const float*)d_in[15];
    const float* fc2_W   = (const float*)d_in[16];
    const float* fc2_b   = (const float*)d_in[17];

    const int* e_src = ei;
    const int* e_dst = ei + N_EDGES;

    char* w = (char*)d_ws;
    float* hA    = (float*)(w);                 // [N,128] 20,480,000 B
    float* hB    = (float*)(w + 20480000);      // [N,128]
    float* as_   = (float*)(w + 40960000);      // [N]
    float* ad_   = (float*)(w + 41120000);      // [N]
    int*   deg   = (int*)  (w + 41280000);      // [N]
    int*   start = (int*)  (w + 41440000);      // [N]
    int*   cursor= (int*)  (w + 41600000);      // [N]
    int*   counter=(int*)  (w + 41760000);      // [1]
    int*   csr   = (int*)  (w + 41760256);      // [ETOT]  (ends ~44.5MB)

    dim3 b(256);
    // ---- CSR build (same for both convs) ----
    k_deg_init  <<<157,  b, 0, stream>>>(deg, counter);
    k_deg_count <<<2500, b, 0, stream>>>(e_dst, deg);
    k_assign    <<<157,  b, 0, stream>>>(deg, counter, start, cursor, csr);
    k_fill_edges<<<2500, b, 0, stream>>>(e_src, e_dst, cursor, csr);

    // ---- encoder: hA = relu(x[:, :64]@satW.T + b) ; hA += 0.5*relu(x[:,64:]@neighW.T + b) ----
    k_gemm<64, EPI_RELU>   <<<625, b, 0, stream>>>(x, 0,  sat_W,   sat_b,   hA, 128, 128);
    k_gemm<64, EPI_ADDHALF><<<625, b, 0, stream>>>(x, 64, neigh_W, neigh_b, hA, 128, 128);

    // ---- conv1 ----
    k_gemm<128, EPI_STORE><<<625, b, 0, stream>>>(hA, 0, c1_W, nullptr, hB, 128, 128);
    k_alpha    <<<10000, b, 0, stream>>>(hB, c1_as, c1_ad, as_, ad_);
    k_aggregate<<<10000, b, 0, stream>>>(hB, as_, ad_, start, deg, csr, c1_b, hA);

    // ---- conv2 ----
    k_gemm<128, EPI_STORE><<<625, b, 0, stream>>>(hA, 0, c2_W, nullptr, hB, 128, 128);
    k_alpha    <<<10000, b, 0, stream>>>(hB, c2_as, c2_ad, as_, ad_);
    k_aggregate<<<10000, b, 0, stream>>>(hB, as_, ad_, start, deg, csr, c2_b, hA);

    // ---- head ----
    k_gemm<128, EPI_RELU><<<625, b, 0, stream>>>(hA, 0, fc1_W, fc1_b, hB, 128, 128);
    k_gemm<128, EPI_BIAS><<<625, b, 0, stream>>>(hB, 0, fc2_W, fc2_b, (float*)d_out, 54, 54);
}

// Round 2
// 340.931 us; speedup vs baseline: 1.3498x; 1.3498x over previous
//
#include <hip/hip_runtime.h>

// Stage2GNN v2: fused encoder -> GAT conv1 -> GAT conv2 -> fc1 -> fc2.
// GEMMs: BK=32 chunked W-staging (16KB LDS, 4 blocks/CU), 4x8 thread tile,
// alpha logits fused into conv GEMM epilogue. Aggregate: 4x-unrolled gather.

#define N_NODES 40000
#define N_EDGES 640000
#define ETOT    (N_NODES + N_EDGES)
#define DIM     128

enum { EPI_RELU = 0, EPI_STORE = 2, EPI_BIAS = 3 };

__device__ __forceinline__ float wave_reduce_max(float v) {
#pragma unroll
    for (int off = 32; off; off >>= 1) v = fmaxf(v, __shfl_xor(v, off));
    return v;
}
__device__ __forceinline__ float wave_reduce_sum(float v) {
#pragma unroll
    for (int off = 32; off; off >>= 1) v += __shfl_xor(v, off);
    return v;
}
__device__ __forceinline__ float dot4acc(float4 a, float4 w, float acc) {
    acc = fmaf(a.x, w.x, acc);
    acc = fmaf(a.y, w.y, acc);
    acc = fmaf(a.z, w.z, acc);
    acc = fmaf(a.w, w.w, acc);
    return acc;
}

// ---------------- CSR build ----------------
__global__ void k_deg_init(int* __restrict__ deg, int* __restrict__ counter) {
    int i = blockIdx.x * 256 + threadIdx.x;
    if (i < N_NODES) deg[i] = 1;  // self loop
    if (i == 0) *counter = 0;
}

__global__ void k_deg_count(const int* __restrict__ dst, int* __restrict__ deg) {
    int t = blockIdx.x * 256 + threadIdx.x;
    if (t < N_EDGES) atomicAdd(&deg[dst[t]], 1);
}

__global__ void k_assign(const int* __restrict__ deg, int* __restrict__ counter,
                         int* __restrict__ start, int* __restrict__ cursor,
                         int* __restrict__ csr_src) {
    int i = blockIdx.x * 256 + threadIdx.x;
    if (i >= N_NODES) return;
    int d = deg[i];
    int s = atomicAdd(counter, d);
    start[i]  = s;
    csr_src[s] = i;      // self loop first
    cursor[i] = s + 1;
}

__global__ void k_fill_edges(const int* __restrict__ src, const int* __restrict__ dst,
                             int* __restrict__ cursor, int* __restrict__ csr_src) {
    int t = blockIdx.x * 256 + threadIdx.x;
    if (t < N_EDGES) {
        int p = atomicAdd(&cursor[dst[t]], 1);
        csr_src[p] = src[t];
    }
}

// ---------------- GEMM chunk: stage W[0..C-1][wko..wko+31] into LDS (swizzled),
// then accumulate 32 k-steps with x read straight from global (L1/L2 broadcast).
template<int WSTRIDE>
__device__ __forceinline__ void gemm_chunk(
    float acc[4][8], const float* __restrict__ Wg, int wko,
    const float* __restrict__ xp, int xko, float* Ws, int tid, int c0, int C)
{
    for (int idx = tid * 4; idx < C * 32; idx += 1024) {
        int c = idx >> 5, k = idx & 31;
        float4 w = *(const float4*)&Wg[c * WSTRIDE + wko + k];
        int ks = (k + ((c >> 3) & 7) * 4) & 31;   // bank swizzle
        *(float4*)&Ws[c * 32 + ks] = w;
    }
    __syncthreads();
#pragma unroll 4
    for (int k0 = 0; k0 < 32; k0 += 4) {
        float4 a0 = *(const float4*)(xp + 0 * DIM + xko + k0);
        float4 a1 = *(const float4*)(xp + 1 * DIM + xko + k0);
        float4 a2 = *(const float4*)(xp + 2 * DIM + xko + k0);
        float4 a3 = *(const float4*)(xp + 3 * DIM + xko + k0);
#pragma unroll
        for (int cc = 0; cc < 8; ++cc) {
            int c = c0 + cc;
            float4 w = *(const float4*)&Ws[c * 32 + ((k0 + ((c >> 3) & 7) * 4) & 31)];
            acc[0][cc] = dot4acc(a0, w, acc[0][cc]);
            acc[1][cc] = dot4acc(a1, w, acc[1][cc]);
            acc[2][cc] = dot4acc(a2, w, acc[2][cc]);
            acc[3][cc] = dot4acc(a3, w, acc[3][cc]);
        }
    }
    __syncthreads();
}

__device__ __forceinline__ float apply_epi(float v, float b, int epi) {
    if (epi == EPI_RELU) return fmaxf(v + b, 0.f);
    if (epi == EPI_BIAS) return v + b;
    return v;
}

template<int K, int EPI, bool ALPHA>
__global__ __launch_bounds__(256, 4) void k_gemm(
    const float* __restrict__ in, const float* __restrict__ W,
    const float* __restrict__ bias, float* __restrict__ out, int C, int out_stride,
    const float* __restrict__ a_src, const float* __restrict__ a_dst,
    float* __restrict__ as_, float* __restrict__ ad_)
{
    __shared__ float Ws[128 * 32];
    const int tid = threadIdx.x;
    const int rowgrp = tid >> 4, colgrp = tid & 15;
    const int r0 = blockIdx.x * 64 + rowgrp * 4;
    const int c0 = colgrp * 8;
    const float* xp = in + (size_t)r0 * DIM;

    float acc[4][8] = {};
    for (int ko = 0; ko < K; ko += 32)
        gemm_chunk<K>(acc, W, ko, xp, ko, Ws, tid, c0, C);

    if constexpr (ALPHA) {
        float asv[8], adv[8];
#pragma unroll
        for (int cc = 0; cc < 8; ++cc) { asv[cc] = a_src[c0 + cc]; adv[cc] = a_dst[c0 + cc]; }
#pragma unroll
        for (int rr = 0; rr < 4; ++rr) {
            float ss = 0.f, dd = 0.f;
#pragma unroll
            for (int cc = 0; cc < 8; ++cc) {
                ss = fmaf(acc[rr][cc], asv[cc], ss);
                dd = fmaf(acc[rr][cc], adv[cc], dd);
            }
#pragma unroll
            for (int off = 1; off < 16; off <<= 1) {
                ss += __shfl_xor(ss, off);
                dd += __shfl_xor(dd, off);
            }
            if (colgrp == 0) { as_[r0 + rr] = ss; ad_[r0 + rr] = dd; }
        }
    }

    float bv[8];
    if constexpr (EPI != EPI_STORE) {
#pragma unroll
        for (int cc = 0; cc < 8; ++cc) bv[cc] = (c0 + cc < C) ? bias[c0 + cc] : 0.f;
    } else {
#pragma unroll
        for (int cc = 0; cc < 8; ++cc) bv[cc] = 0.f;
    }

#pragma unroll
    for (int rr = 0; rr < 4; ++rr) {
        float* orow = out + (size_t)(r0 + rr) * out_stride;
        if (c0 + 7 < C) {
            float4 v0, v1;
            v0.x = apply_epi(acc[rr][0], bv[0], EPI); v0.y = apply_epi(acc[rr][1], bv[1], EPI);
            v0.z = apply_epi(acc[rr][2], bv[2], EPI); v0.w = apply_epi(acc[rr][3], bv[3], EPI);
            v1.x = apply_epi(acc[rr][4], bv[4], EPI); v1.y = apply_epi(acc[rr][5], bv[5], EPI);
            v1.z = apply_epi(acc[rr][6], bv[6], EPI); v1.w = apply_epi(acc[rr][7], bv[7], EPI);
            *(float4*)&orow[c0] = v0;
            *(float4*)&orow[c0 + 4] = v1;
        } else {
#pragma unroll
            for (int cc = 0; cc < 8; ++cc)
                if (c0 + cc < C) orow[c0 + cc] = apply_epi(acc[rr][cc], bv[cc], EPI);
        }
    }
}

// ---------------- fused encoder: h = relu(x[:, :64]@satW.T+sb) + 0.5*relu(x[:,64:]@neiW.T+nb)
__global__ __launch_bounds__(256, 3) void k_encoder(
    const float* __restrict__ x,
    const float* __restrict__ satW, const float* __restrict__ satb,
    const float* __restrict__ neiW, const float* __restrict__ neib,
    float* __restrict__ out)
{
    __shared__ float Ws[128 * 32];
    const int tid = threadIdx.x;
    const int rowgrp = tid >> 4, colgrp = tid & 15;
    const int r0 = blockIdx.x * 64 + rowgrp * 4;
    const int c0 = colgrp * 8;
    const float* xp = x + (size_t)r0 * DIM;

    float accA[4][8] = {}, accB[4][8] = {};
    gemm_chunk<64>(accA, satW, 0,  xp, 0,  Ws, tid, c0, 128);
    gemm_chunk<64>(accA, satW, 32, xp, 32, Ws, tid, c0, 128);
    gemm_chunk<64>(accB, neiW, 0,  xp, 64, Ws, tid, c0, 128);
    gemm_chunk<64>(accB, neiW, 32, xp, 96, Ws, tid, c0, 128);

    float sb[8], nb[8];
#pragma unroll
    for (int cc = 0; cc < 8; ++cc) { sb[cc] = satb[c0 + cc]; nb[cc] = neib[c0 + cc]; }

#pragma unroll
    for (int rr = 0; rr < 4; ++rr) {
        float* orow = out + (size_t)(r0 + rr) * DIM;
        float4 v0, v1;
        v0.x = fmaxf(accA[rr][0] + sb[0], 0.f) + 0.5f * fmaxf(accB[rr][0] + nb[0], 0.f);
        v0.y = fmaxf(accA[rr][1] + sb[1], 0.f) + 0.5f * fmaxf(accB[rr][1] + nb[1], 0.f);
        v0.z = fmaxf(accA[rr][2] + sb[2], 0.f) + 0.5f * fmaxf(accB[rr][2] + nb[2], 0.f);
        v0.w = fmaxf(accA[rr][3] + sb[3], 0.f) + 0.5f * fmaxf(accB[rr][3] + nb[3], 0.f);
        v1.x = fmaxf(accA[rr][4] + sb[4], 0.f) + 0.5f * fmaxf(accB[rr][4] + nb[4], 0.f);
        v1.y = fmaxf(accA[rr][5] + sb[5], 0.f) + 0.5f * fmaxf(accB[rr][5] + nb[5], 0.f);
        v1.z = fmaxf(accA[rr][6] + sb[6], 0.f) + 0.5f * fmaxf(accB[rr][6] + nb[6], 0.f);
        v1.w = fmaxf(accA[rr][7] + sb[7], 0.f) + 0.5f * fmaxf(accB[rr][7] + nb[7], 0.f);
        *(float4*)&orow[c0] = v0;
        *(float4*)&orow[c0 + 4] = v1;
    }
}

// ---------------- wave-per-node softmax + aggregation (4x-unrolled gather) ----------------
__global__ __launch_bounds__(256) void k_aggregate(
    const float* __restrict__ h, const float* __restrict__ as_,
    const float* __restrict__ ad_, const int* __restrict__ start,
    const int* __restrict__ deg, const int* __restrict__ csr_src,
    const float* __restrict__ bias, float* __restrict__ out)
{
    int wid  = (blockIdx.x * 256 + threadIdx.x) >> 6;
    int lane = threadIdx.x & 63;
    if (wid >= N_NODES) return;

    const int s0 = start[wid];
    const int s1 = s0 + deg[wid];
    const float adi = ad_[wid];

    // pass 1: segment max
    float m = -1e30f;
    for (int base = s0; base < s1; base += 64) {
        int k = base + lane;
        if (k < s1) {
            float e = as_[csr_src[k]] + adi;
            e = (e > 0.f) ? e : 0.2f * e;
            m = fmaxf(m, e);
        }
    }
    m = wave_reduce_max(m);

    // pass 2: unnormalized weighted accumulate + weight sum
    float2 acc = make_float2(0.f, 0.f);
    float ssum = 0.f;
    for (int base = s0; base < s1; base += 64) {
        int k = base + lane;
        int cnt = min(64, s1 - base);   // wave-uniform
        int jj = 0;
        float p = 0.f;
        if (k < s1) {
            jj = csr_src[k];
            float e = as_[jj] + adi;
            e = (e > 0.f) ? e : 0.2f * e;
            p = expf(e - m);
            ssum += p;
        }
        int t = 0;
        for (; t + 4 <= cnt; t += 4) {
            float p0 = __uint_as_float(__builtin_amdgcn_readlane(__float_as_uint(p), t));
            float p1 = __uint_as_float(__builtin_amdgcn_readlane(__float_as_uint(p), t + 1));
            float p2 = __uint_as_float(__builtin_amdgcn_readlane(__float_as_uint(p), t + 2));
            float p3 = __uint_as_float(__builtin_amdgcn_readlane(__float_as_uint(p), t + 3));
            int j0 = __builtin_amdgcn_readlane(jj, t);
            int j1 = __builtin_amdgcn_readlane(jj, t + 1);
            int j2 = __builtin_amdgcn_readlane(jj, t + 2);
            int j3 = __builtin_amdgcn_readlane(jj, t + 3);
            float2 h0 = *(const float2*)&h[(size_t)j0 * DIM + 2 * lane];
            float2 h1 = *(const float2*)&h[(size_t)j1 * DIM + 2 * lane];
            float2 h2 = *(const float2*)&h[(size_t)j2 * DIM + 2 * lane];
            float2 h3 = *(const float2*)&h[(size_t)j3 * DIM + 2 * lane];
            acc.x = fmaf(p0, h0.x, acc.x); acc.y = fmaf(p0, h0.y, acc.y);
            acc.x = fmaf(p1, h1.x, acc.x); acc.y = fmaf(p1, h1.y, acc.y);
            acc.x = fmaf(p2, h2.x, acc.x); acc.y = fmaf(p2, h2.y, acc.y);
            acc.x = fmaf(p3, h3.x, acc.x); acc.y = fmaf(p3, h3.y, acc.y);
        }
        for (; t < cnt; ++t) {
            float pt = __uint_as_float(__builtin_amdgcn_readlane(__float_as_uint(p), t));
            int   jt = __builtin_amdgcn_readlane(jj, t);
            float2 hv = *(const float2*)&h[(size_t)jt * DIM + 2 * lane];
            acc.x = fmaf(pt, hv.x, acc.x);
            acc.y = fmaf(pt, hv.y, acc.y);
        }
    }
    ssum = wave_reduce_sum(ssum);
    float inv = 1.f / (ssum + 1e-16f);

    float2 b = *(const float2*)&bias[2 * lane];
    float ox = fmaxf(fmaf(acc.x, inv, b.x), 0.f);
    float oy = fmaxf(fmaf(acc.y, inv, b.y), 0.f);
    *(float2*)&out[(size_t)wid * DIM + 2 * lane] = make_float2(ox, oy);
}

extern "C" void kernel_launch(void* const* d_in, const int* in_sizes, int n_in,
                              void* d_out, int out_size, void* d_ws, size_t ws_size,
                              hipStream_t stream) {
    (void)in_sizes; (void)n_in; (void)out_size; (void)ws_size;

    const float* x       = (const float*)d_in[0];
    const int*   ei      = (const int*)d_in[1];
    const float* sat_W   = (const float*)d_in[2];
    const float* sat_b   = (const float*)d_in[3];
    const float* neigh_W = (const float*)d_in[4];
    const float* neigh_b = (const float*)d_in[5];
    const float* c1_W    = (const float*)d_in[6];
    const float* c1_as   = (const float*)d_in[7];
    const float* c1_ad   = (const float*)d_in[8];
    const float* c1_b    = (const float*)d_in[9];
    const float* c2_W    = (const float*)d_in[10];
    const float* c2_as   = (const float*)d_in[11];
    const float* c2_ad   = (const float*)d_in[12];
    const float* c2_b    = (const float*)d_in[13];
    const float* fc1_W   = (const float*)d_in[14];
    const float* fc1_b   = (const float*)d_in[15];
    const float* fc2_W   = (const float*)d_in[16];
    const float* fc2_b   = (const float*)d_in[17];

    const int* e_src = ei;
    const int* e_dst = ei + N_EDGES;

    char* w = (char*)d_ws;
    float* hA    = (float*)(w);                 // [N,128]
    float* hB    = (float*)(w + 20480000);      // [N,128]
    float* as_   = (float*)(w + 40960000);      // [N]
    float* ad_   = (float*)(w + 41120000);      // [N]
    int*   deg   = (int*)  (w + 41280000);      // [N]
    int*   start = (int*)  (w + 41440000);      // [N]
    int*   cursor= (int*)  (w + 41600000);      // [N]
    int*   counter=(int*)  (w + 41760000);      // [1]
    int*   csr   = (int*)  (w + 41760256);      // [ETOT]

    dim3 b(256);
    k_deg_init  <<<157,  b, 0, stream>>>(deg, counter);
    k_deg_count <<<2500, b, 0, stream>>>(e_dst, deg);
    k_assign    <<<157,  b, 0, stream>>>(deg, counter, start, cursor, csr);
    k_fill_edges<<<2500, b, 0, stream>>>(e_src, e_dst, cursor, csr);

    k_encoder<<<625, b, 0, stream>>>(x, sat_W, sat_b, neigh_W, neigh_b, hA);

    k_gemm<128, EPI_STORE, true><<<625, b, 0, stream>>>(
        hA, c1_W, nullptr, hB, 128, 128, c1_as, c1_ad, as_, ad_);
    k_aggregate<<<10000, b, 0, stream>>>(hB, as_, ad_, start, deg, csr, c1_b, hA);

    k_gemm<128, EPI_STORE, true><<<625, b, 0, stream>>>(
        hA, c2_W, nullptr, hB, 128, 128, c2_as, c2_ad, as_, ad_);
    k_aggregate<<<10000, b, 0, stream>>>(hB, as_, ad_, start, deg, csr, c2_b, hA);

    k_gemm<128, EPI_RELU, false><<<625, b, 0, stream>>>(
        hA, fc1_W, fc1_b, hB, 128, 128, nullptr, nullptr, nullptr, nullptr);
    k_gemm<128, EPI_BIAS, false><<<625, b, 0, stream>>>(
        hB, fc2_W, fc2_b, (float*)d_out, 54, 54, nullptr, nullptr, nullptr, nullptr);
}

// Round 3
// 287.816 us; speedup vs baseline: 1.5989x; 1.1845x over previous
//
#include <hip/hip_runtime.h>

// Stage2GNN v3: all GEMMs via split-bf16 MFMA (hi/lo, 3 products -> ~fp32
// accurate), B staged in LDS pre-swizzled into fragment order (conflict-free).
// Aggregate: single-pass softmax (no max shift; |logit| << 88), 8-deep
// unrolled gather, epilogue emits bf16 hi/lo for the next GEMM.

#define N_NODES 40000
#define N_EDGES 640000
#define DIM     128

typedef unsigned short u16;
typedef __attribute__((ext_vector_type(8))) short bf16x8;
typedef __attribute__((ext_vector_type(4))) float f32x4;

__device__ __forceinline__ u16 f2bf(float v) {
    unsigned u = __float_as_uint(v);
    u += 0x7FFFu + ((u >> 16) & 1u);
    return (u16)(u >> 16);
}
__device__ __forceinline__ float bf2f(u16 h) { return __uint_as_float(((unsigned)h) << 16); }

// ---------------- input/weight conversion to bf16 hi/lo ----------------
__global__ __launch_bounds__(256) void k_xcvt(const float* __restrict__ x,
                                              u16* __restrict__ xh, u16* __restrict__ xl) {
    int i = blockIdx.x * 256 + threadIdx.x;       // float4 index
    const int n4 = N_NODES * DIM / 4;
    if (i >= n4) return;
    float4 v = ((const float4*)x)[i];
    u16 h0 = f2bf(v.x), h1 = f2bf(v.y), h2 = f2bf(v.z), h3 = f2bf(v.w);
    u16 l0 = f2bf(v.x - bf2f(h0)), l1 = f2bf(v.y - bf2f(h1));
    u16 l2 = f2bf(v.z - bf2f(h2)), l3 = f2bf(v.w - bf2f(h3));
    ((ushort4*)xh)[i] = make_ushort4(h0, h1, h2, h3);
    ((ushort4*)xl)[i] = make_ushort4(l0, l1, l2, l3);
}

__global__ __launch_bounds__(256) void k_wcvt(
    const float* __restrict__ satW, const float* __restrict__ neiW,
    const float* __restrict__ c1W, const float* __restrict__ c2W,
    const float* __restrict__ f1W, const float* __restrict__ f2W,
    u16* __restrict__ wa) {
    int m = blockIdx.y;
    const float* src; int C, K, Cp; int offH, offL;
    switch (m) {
        case 0: src = satW; C = 128; K = 64;  Cp = 128; offH = 0;      offL = 8192;   break;
        case 1: src = neiW; C = 128; K = 64;  Cp = 128; offH = 16384;  offL = 24576;  break;
        case 2: src = c1W;  C = 128; K = 128; Cp = 128; offH = 32768;  offL = 49152;  break;
        case 3: src = c2W;  C = 128; K = 128; Cp = 128; offH = 65536;  offL = 81920;  break;
        case 4: src = f1W;  C = 128; K = 128; Cp = 128; offH = 98304;  offL = 114688; break;
        default:src = f2W;  C = 54;  K = 128; Cp = 64;  offH = 131072; offL = 139264; break;
    }
    int e = blockIdx.x * 256 + threadIdx.x;
    if (e >= Cp * K) return;
    int c = e / K, k = e - c * K;
    float v = (c < C) ? src[c * K + k] : 0.f;
    u16 h = f2bf(v);
    wa[offH + e] = h;
    wa[offL + e] = f2bf(v - bf2f(h));
}

// ---------------- CSR build ----------------
__global__ void k_deg_init(int* __restrict__ deg, int* __restrict__ counter) {
    int i = blockIdx.x * 256 + threadIdx.x;
    if (i < N_NODES) deg[i] = 1;
    if (i == 0) *counter = 0;
}
__global__ void k_deg_count(const int* __restrict__ dst, int* __restrict__ deg) {
    int t = blockIdx.x * 256 + threadIdx.x;
    if (t < N_EDGES) atomicAdd(&deg[dst[t]], 1);
}
__global__ void k_assign(const int* __restrict__ deg, int* __restrict__ counter,
                         int* __restrict__ start, int* __restrict__ cursor,
                         int* __restrict__ csr_src) {
    int i = blockIdx.x * 256 + threadIdx.x;
    if (i >= N_NODES) return;
    int d = deg[i];
    int s = atomicAdd(counter, d);
    start[i] = s;
    csr_src[s] = i;
    cursor[i] = s + 1;
}
__global__ void k_fill_edges(const int* __restrict__ src, const int* __restrict__ dst,
                             int* __restrict__ cursor, int* __restrict__ csr_src) {
    int t = blockIdx.x * 256 + threadIdx.x;
    if (t < N_EDGES) {
        int p = atomicAdd(&cursor[dst[t]], 1);
        csr_src[p] = src[t];
    }
}

// ---------------- MFMA GEMM: out[r][c] = sum_k A[r][k]*W[c][k], K=128 ----------------
enum { EPI_F32RAW = 0, EPI_RELU_BF16 = 1, EPI_BIAS_F32 = 2 };

template<int CT, bool ALPHA, int EPI>
__global__ __launch_bounds__(256) void k_mfma_gemm(
    const u16* __restrict__ Ah, const u16* __restrict__ Al,
    const u16* __restrict__ Wh, const u16* __restrict__ Wl,
    const float* __restrict__ bias, int C,
    float* __restrict__ outF, int ldo,
    u16* __restrict__ outH, u16* __restrict__ outL,
    const float* __restrict__ a_src, const float* __restrict__ a_dst,
    float* __restrict__ as_, float* __restrict__ ad_)
{
    __shared__ u16 Ws[CT * 4 * 2 * 64 * 8];
    const int tid = threadIdx.x;

    for (int idx = tid; idx < CT * 4 * 2 * 64; idx += 256) {
        int lane = idx & 63;
        int q = idx >> 6;
        int hilo = q & 1;
        int q2 = q >> 1;
        int ks = q2 & 3, ct = q2 >> 2;
        int c = ct * 16 + (lane & 15);
        int k = ks * 32 + (lane >> 4) * 8;
        const u16* Wp = hilo ? Wl : Wh;
        bf16x8 wv_ = *reinterpret_cast<const bf16x8*>(Wp + (size_t)c * 128 + k);
        *reinterpret_cast<bf16x8*>(&Ws[idx * 8]) = wv_;
    }
    __syncthreads();

    const int lane = tid & 63;
    const int wv = tid >> 6;
    const int r0 = blockIdx.x * 64 + wv * 16;
    const int arow = r0 + (lane & 15);
    const int kb = (lane >> 4) * 8;

    bf16x8 ah[4], al[4];
#pragma unroll
    for (int s = 0; s < 4; ++s) {
        ah[s] = *reinterpret_cast<const bf16x8*>(Ah + (size_t)arow * 128 + s * 32 + kb);
        al[s] = *reinterpret_cast<const bf16x8*>(Al + (size_t)arow * 128 + s * 32 + kb);
    }

    f32x4 acc[CT];
#pragma unroll
    for (int ct = 0; ct < CT; ++ct) acc[ct] = (f32x4){0.f, 0.f, 0.f, 0.f};

#pragma unroll
    for (int ct = 0; ct < CT; ++ct) {
#pragma unroll
        for (int s = 0; s < 4; ++s) {
            const int base = ((ct * 4 + s) * 2) * 64 * 8;
            bf16x8 bh = *reinterpret_cast<const bf16x8*>(&Ws[base + lane * 8]);
            bf16x8 bl = *reinterpret_cast<const bf16x8*>(&Ws[base + 64 * 8 + lane * 8]);
            acc[ct] = __builtin_amdgcn_mfma_f32_16x16x32_bf16(ah[s], bh, acc[ct], 0, 0, 0);
            acc[ct] = __builtin_amdgcn_mfma_f32_16x16x32_bf16(ah[s], bl, acc[ct], 0, 0, 0);
            acc[ct] = __builtin_amdgcn_mfma_f32_16x16x32_bf16(al[s], bh, acc[ct], 0, 0, 0);
        }
    }

    if constexpr (ALPHA) {
        float ps[4] = {0, 0, 0, 0}, pd[4] = {0, 0, 0, 0};
#pragma unroll
        for (int ct = 0; ct < CT; ++ct) {
            float asv = a_src[ct * 16 + (lane & 15)];
            float adv = a_dst[ct * 16 + (lane & 15)];
#pragma unroll
            for (int r = 0; r < 4; ++r) {
                ps[r] = fmaf(acc[ct][r], asv, ps[r]);
                pd[r] = fmaf(acc[ct][r], adv, pd[r]);
            }
        }
#pragma unroll
        for (int off = 1; off < 16; off <<= 1) {
#pragma unroll
            for (int r = 0; r < 4; ++r) {
                ps[r] += __shfl_xor(ps[r], off);
                pd[r] += __shfl_xor(pd[r], off);
            }
        }
        if ((lane & 15) == 0) {
#pragma unroll
            for (int r = 0; r < 4; ++r) {
                int row = r0 + (lane >> 4) * 4 + r;
                as_[row] = ps[r];
                ad_[row] = pd[r];
            }
        }
    }

#pragma unroll
    for (int ct = 0; ct < CT; ++ct) {
        int c = ct * 16 + (lane & 15);
#pragma unroll
        for (int r = 0; r < 4; ++r) {
            int row = r0 + (lane >> 4) * 4 + r;
            float v = acc[ct][r];
            if constexpr (EPI == EPI_F32RAW) {
                outF[(size_t)row * ldo + c] = v;
            } else if constexpr (EPI == EPI_RELU_BF16) {
                v = fmaxf(v + bias[c], 0.f);
                u16 h = f2bf(v);
                outH[(size_t)row * 128 + c] = h;
                outL[(size_t)row * 128 + c] = f2bf(v - bf2f(h));
            } else {
                if (c < C) outF[(size_t)row * ldo + c] = v + bias[c];
            }
        }
    }
}

// ---------------- fused encoder (two K=64 split-bf16 MFMA GEMMs) ----------------
__global__ __launch_bounds__(256) void k_encoder(
    const u16* __restrict__ xh, const u16* __restrict__ xl,
    const u16* __restrict__ sH, const u16* __restrict__ sL,
    const u16* __restrict__ nH, const u16* __restrict__ nL,
    const float* __restrict__ satb, const float* __restrict__ neib,
    u16* __restrict__ outH, u16* __restrict__ outL)
{
    __shared__ u16 Ws[4096 * 8];   // [mat2][ct8][ks2][hilo2][lane64] x 16B = 64KB
    const int tid = threadIdx.x;
    for (int idx = tid; idx < 4096; idx += 256) {
        int mat = idx >> 11;
        int sub = idx & 2047;
        int lane = sub & 63;
        int q = sub >> 6;
        int hilo = q & 1;
        int ks = (q >> 1) & 1;
        int ct = q >> 2;
        int c = ct * 16 + (lane & 15);
        int k = ks * 32 + (lane >> 4) * 8;
        const u16* Wp = mat ? (hilo ? nL : nH) : (hilo ? sL : sH);
        bf16x8 wv_ = *reinterpret_cast<const bf16x8*>(Wp + (size_t)c * 64 + k);
        *reinterpret_cast<bf16x8*>(&Ws[idx * 8]) = wv_;
    }
    __syncthreads();

    const int lane = tid & 63;
    const int wv = tid >> 6;
    const int r0 = blockIdx.x * 64 + wv * 16;
    const int arow = r0 + (lane & 15);
    const int kb = (lane >> 4) * 8;

    bf16x8 axh[4], axl[4];
#pragma unroll
    for (int s = 0; s < 4; ++s) {
        axh[s] = *reinterpret_cast<const bf16x8*>(xh + (size_t)arow * 128 + s * 32 + kb);
        axl[s] = *reinterpret_cast<const bf16x8*>(xl + (size_t)arow * 128 + s * 32 + kb);
    }

    f32x4 accS[8], accN[8];
#pragma unroll
    for (int ct = 0; ct < 8; ++ct) { accS[ct] = (f32x4){0,0,0,0}; accN[ct] = (f32x4){0,0,0,0}; }

#pragma unroll
    for (int ct = 0; ct < 8; ++ct) {
#pragma unroll
        for (int s = 0; s < 2; ++s) {
            int baseS = ((ct * 2 + s) * 2) * 64 * 8;
            int baseN = baseS + 2048 * 8;
            bf16x8 bsh = *reinterpret_cast<const bf16x8*>(&Ws[baseS + lane * 8]);
            bf16x8 bsl = *reinterpret_cast<const bf16x8*>(&Ws[baseS + 512 + lane * 8]);
            bf16x8 bnh = *reinterpret_cast<const bf16x8*>(&Ws[baseN + lane * 8]);
            bf16x8 bnl = *reinterpret_cast<const bf16x8*>(&Ws[baseN + 512 + lane * 8]);
            accS[ct] = __builtin_amdgcn_mfma_f32_16x16x32_bf16(axh[s], bsh, accS[ct], 0, 0, 0);
            accS[ct] = __builtin_amdgcn_mfma_f32_16x16x32_bf16(axh[s], bsl, accS[ct], 0, 0, 0);
            accS[ct] = __builtin_amdgcn_mfma_f32_16x16x32_bf16(axl[s], bsh, accS[ct], 0, 0, 0);
            accN[ct] = __builtin_amdgcn_mfma_f32_16x16x32_bf16(axh[s + 2], bnh, accN[ct], 0, 0, 0);
            accN[ct] = __builtin_amdgcn_mfma_f32_16x16x32_bf16(axh[s + 2], bnl, accN[ct], 0, 0, 0);
            accN[ct] = __builtin_amdgcn_mfma_f32_16x16x32_bf16(axl[s + 2], bnh, accN[ct], 0, 0, 0);
        }
    }

#pragma unroll
    for (int ct = 0; ct < 8; ++ct) {
        int c = ct * 16 + (lane & 15);
        float bs = satb[c], bn = neib[c];
#pragma unroll
        for (int r = 0; r < 4; ++r) {
            int row = r0 + (lane >> 4) * 4 + r;
            float v = fmaxf(accS[ct][r] + bs, 0.f) + 0.5f * fmaxf(accN[ct][r] + bn, 0.f);
            u16 h = f2bf(v);
            outH[(size_t)row * 128 + c] = h;
            outL[(size_t)row * 128 + c] = f2bf(v - bf2f(h));
        }
    }
}

// ---------------- wave-per-node softmax + aggregation (single pass) ----------------
__global__ __launch_bounds__(256) void k_aggregate(
    const float* __restrict__ h, const float* __restrict__ as_,
    const float* __restrict__ ad_, const int* __restrict__ start,
    const int* __restrict__ deg, const int* __restrict__ csr_src,
    const float* __restrict__ bias, u16* __restrict__ outH, u16* __restrict__ outL)
{
    int wid = (blockIdx.x * 256 + threadIdx.x) >> 6;
    int lane = threadIdx.x & 63;
    if (wid >= N_NODES) return;

    const int s0 = start[wid];
    const int s1 = s0 + deg[wid];
    const float adi = ad_[wid];

    float2 acc = make_float2(0.f, 0.f);
    float ssum = 0.f;
    for (int base = s0; base < s1; base += 64) {
        int k = base + lane;
        int cnt = min(64, s1 - base);   // wave-uniform
        int jj = 0;
        float p = 0.f;
        if (k < s1) {
            jj = csr_src[k];
            float e = as_[jj] + adi;
            e = (e > 0.f) ? e : 0.2f * e;
            p = __expf(e);              // |e| << 88: no max-shift needed
            ssum += p;
        }
        int t = 0;
        for (; t + 8 <= cnt; t += 8) {
            float pv[8]; int jv[8];
#pragma unroll
            for (int q = 0; q < 8; ++q) {
                pv[q] = __uint_as_float(__builtin_amdgcn_readlane(__float_as_uint(p), t + q));
                jv[q] = __builtin_amdgcn_readlane(jj, t + q);
            }
            float2 hv[8];
#pragma unroll
            for (int q = 0; q < 8; ++q) hv[q] = *(const float2*)&h[(size_t)jv[q] * DIM + 2 * lane];
#pragma unroll
            for (int q = 0; q < 8; ++q) {
                acc.x = fmaf(pv[q], hv[q].x, acc.x);
                acc.y = fmaf(pv[q], hv[q].y, acc.y);
            }
        }
        for (; t < cnt; ++t) {
            float pt = __uint_as_float(__builtin_amdgcn_readlane(__float_as_uint(p), t));
            int jt = __builtin_amdgcn_readlane(jj, t);
            float2 hv = *(const float2*)&h[(size_t)jt * DIM + 2 * lane];
            acc.x = fmaf(pt, hv.x, acc.x);
            acc.y = fmaf(pt, hv.y, acc.y);
        }
    }
#pragma unroll
    for (int off = 32; off; off >>= 1) ssum += __shfl_xor(ssum, off);
    float inv = 1.f / (ssum + 1e-16f);

    float2 b = *(const float2*)&bias[2 * lane];
    float ox = fmaxf(fmaf(acc.x, inv, b.x), 0.f);
    float oy = fmaxf(fmaf(acc.y, inv, b.y), 0.f);
    u16 hx = f2bf(ox), hy = f2bf(oy);
    u16 lx = f2bf(ox - bf2f(hx)), ly = f2bf(oy - bf2f(hy));
    unsigned hw = (unsigned)hx | ((unsigned)hy << 16);
    unsigned lw = (unsigned)lx | ((unsigned)ly << 16);
    *(unsigned*)&outH[(size_t)wid * 128 + 2 * lane] = hw;
    *(unsigned*)&outL[(size_t)wid * 128 + 2 * lane] = lw;
}

extern "C" void kernel_launch(void* const* d_in, const int* in_sizes, int n_in,
                              void* d_out, int out_size, void* d_ws, size_t ws_size,
                              hipStream_t stream) {
    (void)in_sizes; (void)n_in; (void)out_size; (void)ws_size;

    const float* x       = (const float*)d_in[0];
    const int*   ei      = (const int*)d_in[1];
    const float* sat_W   = (const float*)d_in[2];
    const float* sat_b   = (const float*)d_in[3];
    const float* neigh_W = (const float*)d_in[4];
    const float* neigh_b = (const float*)d_in[5];
    const float* c1_W    = (const float*)d_in[6];
    const float* c1_as   = (const float*)d_in[7];
    const float* c1_ad   = (const float*)d_in[8];
    const float* c1_b    = (const float*)d_in[9];
    const float* c2_W    = (const float*)d_in[10];
    const float* c2_as   = (const float*)d_in[11];
    const float* c2_ad   = (const float*)d_in[12];
    const float* c2_b    = (const float*)d_in[13];
    const float* fc1_W   = (const float*)d_in[14];
    const float* fc1_b   = (const float*)d_in[15];
    const float* fc2_W   = (const float*)d_in[16];
    const float* fc2_b   = (const float*)d_in[17];

    const int* e_src = ei;
    const int* e_dst = ei + N_EDGES;

    char* w = (char*)d_ws;
    float* hB     = (float*)(w);                  // [N,128] f32
    u16*   xH     = (u16*)  (w + 20480000);
    u16*   xL     = (u16*)  (w + 30720000);
    u16*   hH     = (u16*)  (w + 40960000);
    u16*   hL     = (u16*)  (w + 51200000);
    float* as_    = (float*)(w + 61440000);
    float* ad_    = (float*)(w + 61600000);
    int*   deg    = (int*)  (w + 61760000);
    int*   start  = (int*)  (w + 61920000);
    int*   cursor = (int*)  (w + 62080000);
    int*   counter= (int*)  (w + 62240000);
    int*   csr    = (int*)  (w + 62240256);
    u16*   wa     = (u16*)  (w + 64960512);

    u16 *satH = wa,          *satL = wa + 8192;
    u16 *neiH = wa + 16384,  *neiL = wa + 24576;
    u16 *c1H  = wa + 32768,  *c1L  = wa + 49152;
    u16 *c2H  = wa + 65536,  *c2L  = wa + 81920;
    u16 *f1H  = wa + 98304,  *f1L  = wa + 114688;
    u16 *f2H  = wa + 131072, *f2L  = wa + 139264;

    dim3 b(256);
    k_wcvt<<<dim3(64, 6), b, 0, stream>>>(sat_W, neigh_W, c1_W, c2_W, fc1_W, fc2_W, wa);
    k_xcvt<<<5000, b, 0, stream>>>(x, xH, xL);

    k_deg_init  <<<157,  b, 0, stream>>>(deg, counter);
    k_deg_count <<<2500, b, 0, stream>>>(e_dst, deg);
    k_assign    <<<157,  b, 0, stream>>>(deg, counter, start, cursor, csr);
    k_fill_edges<<<2500, b, 0, stream>>>(e_src, e_dst, cursor, csr);

    k_encoder<<<625, b, 0, stream>>>(xH, xL, satH, satL, neiH, neiL, sat_b, neigh_b, hH, hL);

    k_mfma_gemm<8, true, EPI_F32RAW><<<625, b, 0, stream>>>(
        hH, hL, c1H, c1L, nullptr, 128, hB, 128, nullptr, nullptr,
        c1_as, c1_ad, as_, ad_);
    k_aggregate<<<10000, b, 0, stream>>>(hB, as_, ad_, start, deg, csr, c1_b, hH, hL);

    k_mfma_gemm<8, true, EPI_F32RAW><<<625, b, 0, stream>>>(
        hH, hL, c2H, c2L, nullptr, 128, hB, 128, nullptr, nullptr,
        c2_as, c2_ad, as_, ad_);
    k_aggregate<<<10000, b, 0, stream>>>(hB, as_, ad_, start, deg, csr, c2_b, hH, hL);

    k_mfma_gemm<8, false, EPI_RELU_BF16><<<625, b, 0, stream>>>(
        hH, hL, f1H, f1L, fc1_b, 128, nullptr, 0, xH, xL,
        nullptr, nullptr, nullptr, nullptr);
    k_mfma_gemm<4, false, EPI_BIAS_F32><<<625, b, 0, stream>>>(
        xH, xL, f2H, f2L, fc2_b, 54, (float*)d_out, 54, nullptr, nullptr,
        nullptr, nullptr, nullptr, nullptr);
}

// Round 4
// 264.225 us; speedup vs baseline: 1.7416x; 1.0893x over previous
//
#include <hip/hip_runtime.h>

// Stage2GNN v4: split-bf16 MFMA GEMMs with BK=64 K-chunked W staging (32KB LDS,
// ~5 blocks/CU); aggregate gathers 2 edge-rows per wave-op via float4 lanes
// (16 edges / unrolled body) for 2x bytes-in-flight; deg_init folded into xcvt.

#define N_NODES 40000
#define N_EDGES 640000
#define DIM     128

typedef unsigned short u16;
typedef __attribute__((ext_vector_type(8))) short bf16x8;
typedef __attribute__((ext_vector_type(4))) float f32x4;

__device__ __forceinline__ u16 f2bf(float v) {
    unsigned u = __float_as_uint(v);
    u += 0x7FFFu + ((u >> 16) & 1u);
    return (u16)(u >> 16);
}
__device__ __forceinline__ float bf2f(u16 h) { return __uint_as_float(((unsigned)h) << 16); }
__device__ __forceinline__ float rdlane_f(float v, int l) {
    return __uint_as_float(__builtin_amdgcn_readlane(__float_as_uint(v), l));
}

// ---------------- input conversion + deg init ----------------
__global__ __launch_bounds__(256) void k_xcvt(const float* __restrict__ x,
                                              u16* __restrict__ xh, u16* __restrict__ xl,
                                              int* __restrict__ deg, int* __restrict__ counter) {
    int i = blockIdx.x * 256 + threadIdx.x;       // float4 index
    if (i < N_NODES) deg[i] = 1;                  // self loop
    if (i == 0) *counter = 0;
    const int n4 = N_NODES * DIM / 4;
    if (i >= n4) return;
    float4 v = ((const float4*)x)[i];
    u16 h0 = f2bf(v.x), h1 = f2bf(v.y), h2 = f2bf(v.z), h3 = f2bf(v.w);
    u16 l0 = f2bf(v.x - bf2f(h0)), l1 = f2bf(v.y - bf2f(h1));
    u16 l2 = f2bf(v.z - bf2f(h2)), l3 = f2bf(v.w - bf2f(h3));
    ((ushort4*)xh)[i] = make_ushort4(h0, h1, h2, h3);
    ((ushort4*)xl)[i] = make_ushort4(l0, l1, l2, l3);
}

__global__ __launch_bounds__(256) void k_wcvt(
    const float* __restrict__ satW, const float* __restrict__ neiW,
    const float* __restrict__ c1W, const float* __restrict__ c2W,
    const float* __restrict__ f1W, const float* __restrict__ f2W,
    u16* __restrict__ wa) {
    int m = blockIdx.y;
    const float* src; int C, K, Cp; int offH, offL;
    switch (m) {
        case 0: src = satW; C = 128; K = 64;  Cp = 128; offH = 0;      offL = 8192;   break;
        case 1: src = neiW; C = 128; K = 64;  Cp = 128; offH = 16384;  offL = 24576;  break;
        case 2: src = c1W;  C = 128; K = 128; Cp = 128; offH = 32768;  offL = 49152;  break;
        case 3: src = c2W;  C = 128; K = 128; Cp = 128; offH = 65536;  offL = 81920;  break;
        case 4: src = f1W;  C = 128; K = 128; Cp = 128; offH = 98304;  offL = 114688; break;
        default:src = f2W;  C = 54;  K = 128; Cp = 64;  offH = 131072; offL = 139264; break;
    }
    int e = blockIdx.x * 256 + threadIdx.x;
    if (e >= Cp * K) return;
    int c = e / K, k = e - c * K;
    float v = (c < C) ? src[c * K + k] : 0.f;
    u16 h = f2bf(v);
    wa[offH + e] = h;
    wa[offL + e] = f2bf(v - bf2f(h));
}

// ---------------- CSR build ----------------
__global__ void k_deg_count(const int* __restrict__ dst, int* __restrict__ deg) {
    int t = blockIdx.x * 256 + threadIdx.x;
    if (t < N_EDGES) atomicAdd(&deg[dst[t]], 1);
}
__global__ void k_assign(const int* __restrict__ deg, int* __restrict__ counter,
                         int* __restrict__ start, int* __restrict__ cursor,
                         int* __restrict__ csr_src) {
    int i = blockIdx.x * 256 + threadIdx.x;
    if (i >= N_NODES) return;
    int d = deg[i];
    int s = atomicAdd(counter, d);
    start[i] = s;
    csr_src[s] = i;
    cursor[i] = s + 1;
}
__global__ void k_fill_edges(const int* __restrict__ src, const int* __restrict__ dst,
                             int* __restrict__ cursor, int* __restrict__ csr_src) {
    int t = blockIdx.x * 256 + threadIdx.x;
    if (t < N_EDGES) {
        int p = atomicAdd(&cursor[dst[t]], 1);
        csr_src[p] = src[t];
    }
}

// ---------------- MFMA GEMM: out[r][c] = sum_k A[r][k]*W[c][k], K=128 ----------------
// Split bf16: acc += Ah*Wh + Ah*Wl + Al*Wh. BK=64 chunked W staging (32KB LDS).
enum { EPI_F32RAW = 0, EPI_RELU_BF16 = 1, EPI_BIAS_F32 = 2 };

template<int CT, bool ALPHA, int EPI>
__global__ __launch_bounds__(256) void k_mfma_gemm(
    const u16* __restrict__ Ah, const u16* __restrict__ Al,
    const u16* __restrict__ Wh, const u16* __restrict__ Wl,
    const float* __restrict__ bias, int C,
    float* __restrict__ outF, int ldo,
    u16* __restrict__ outH, u16* __restrict__ outL,
    const float* __restrict__ a_src, const float* __restrict__ a_dst,
    float* __restrict__ as_, float* __restrict__ ad_)
{
    __shared__ u16 Ws[CT * 2 * 2 * 64 * 8];   // [ct][ks2][hilo2][lane64] x 8 u16
    const int tid = threadIdx.x;
    const int lane = tid & 63;
    const int wv = tid >> 6;
    const int r0 = blockIdx.x * 64 + wv * 16;
    const int arow = r0 + (lane & 15);
    const int kb = (lane >> 4) * 8;

    bf16x8 ah[4], al[4];
#pragma unroll
    for (int s = 0; s < 4; ++s) {
        ah[s] = *reinterpret_cast<const bf16x8*>(Ah + (size_t)arow * 128 + s * 32 + kb);
        al[s] = *reinterpret_cast<const bf16x8*>(Al + (size_t)arow * 128 + s * 32 + kb);
    }

    f32x4 acc[CT];
#pragma unroll
    for (int ct = 0; ct < CT; ++ct) acc[ct] = (f32x4){0.f, 0.f, 0.f, 0.f};

#pragma unroll
    for (int kc = 0; kc < 2; ++kc) {
        if (kc) __syncthreads();
        for (int idx = tid; idx < CT * 2 * 2 * 64; idx += 256) {
            int l = idx & 63;
            int q = idx >> 6;
            int hilo = q & 1;
            int ks = (q >> 1) & 1;
            int ct = q >> 2;
            int c = ct * 16 + (l & 15);
            int k = kc * 64 + ks * 32 + (l >> 4) * 8;
            const u16* Wp = hilo ? Wl : Wh;
            bf16x8 wv_ = *reinterpret_cast<const bf16x8*>(Wp + (size_t)c * 128 + k);
            *reinterpret_cast<bf16x8*>(&Ws[idx * 8]) = wv_;
        }
        __syncthreads();
#pragma unroll
        for (int ct = 0; ct < CT; ++ct) {
#pragma unroll
            for (int ks = 0; ks < 2; ++ks) {
                int s = kc * 2 + ks;
                int base = (ct * 2 + ks) * 1024;
                bf16x8 bh = *reinterpret_cast<const bf16x8*>(&Ws[base + lane * 8]);
                bf16x8 bl = *reinterpret_cast<const bf16x8*>(&Ws[base + 512 + lane * 8]);
                acc[ct] = __builtin_amdgcn_mfma_f32_16x16x32_bf16(ah[s], bh, acc[ct], 0, 0, 0);
                acc[ct] = __builtin_amdgcn_mfma_f32_16x16x32_bf16(ah[s], bl, acc[ct], 0, 0, 0);
                acc[ct] = __builtin_amdgcn_mfma_f32_16x16x32_bf16(al[s], bh, acc[ct], 0, 0, 0);
            }
        }
    }

    if constexpr (ALPHA) {
        float ps[4] = {0, 0, 0, 0}, pd[4] = {0, 0, 0, 0};
#pragma unroll
        for (int ct = 0; ct < CT; ++ct) {
            float asv = a_src[ct * 16 + (lane & 15)];
            float adv = a_dst[ct * 16 + (lane & 15)];
#pragma unroll
            for (int r = 0; r < 4; ++r) {
                ps[r] = fmaf(acc[ct][r], asv, ps[r]);
                pd[r] = fmaf(acc[ct][r], adv, pd[r]);
            }
        }
#pragma unroll
        for (int off = 1; off < 16; off <<= 1) {
#pragma unroll
            for (int r = 0; r < 4; ++r) {
                ps[r] += __shfl_xor(ps[r], off);
                pd[r] += __shfl_xor(pd[r], off);
            }
        }
        if ((lane & 15) == 0) {
#pragma unroll
            for (int r = 0; r < 4; ++r) {
                int row = r0 + (lane >> 4) * 4 + r;
                as_[row] = ps[r];
                ad_[row] = pd[r];
            }
        }
    }

#pragma unroll
    for (int ct = 0; ct < CT; ++ct) {
        int c = ct * 16 + (lane & 15);
#pragma unroll
        for (int r = 0; r < 4; ++r) {
            int row = r0 + (lane >> 4) * 4 + r;
            float v = acc[ct][r];
            if constexpr (EPI == EPI_F32RAW) {
                outF[(size_t)row * ldo + c] = v;
            } else if constexpr (EPI == EPI_RELU_BF16) {
                v = fmaxf(v + bias[c], 0.f);
                u16 h = f2bf(v);
                outH[(size_t)row * 128 + c] = h;
                outL[(size_t)row * 128 + c] = f2bf(v - bf2f(h));
            } else {
                if (c < C) outF[(size_t)row * ldo + c] = v + bias[c];
            }
        }
    }
}

// ---------------- fused encoder (two K=64 split-bf16 MFMA GEMMs, staged serially) ----------------
__global__ __launch_bounds__(256) void k_encoder(
    const u16* __restrict__ xh, const u16* __restrict__ xl,
    const u16* __restrict__ sH, const u16* __restrict__ sL,
    const u16* __restrict__ nH, const u16* __restrict__ nL,
    const float* __restrict__ satb, const float* __restrict__ neib,
    u16* __restrict__ outH, u16* __restrict__ outL)
{
    __shared__ u16 Ws[8 * 2 * 2 * 64 * 8];   // 32KB
    const int tid = threadIdx.x;
    const int lane = tid & 63;
    const int wv = tid >> 6;
    const int r0 = blockIdx.x * 64 + wv * 16;
    const int arow = r0 + (lane & 15);
    const int kb = (lane >> 4) * 8;

    bf16x8 axh[4], axl[4];
#pragma unroll
    for (int s = 0; s < 4; ++s) {
        axh[s] = *reinterpret_cast<const bf16x8*>(xh + (size_t)arow * 128 + s * 32 + kb);
        axl[s] = *reinterpret_cast<const bf16x8*>(xl + (size_t)arow * 128 + s * 32 + kb);
    }

    f32x4 accS[8], accN[8];
#pragma unroll
    for (int ct = 0; ct < 8; ++ct) { accS[ct] = (f32x4){0,0,0,0}; accN[ct] = (f32x4){0,0,0,0}; }

#pragma unroll
    for (int mat = 0; mat < 2; ++mat) {
        if (mat) __syncthreads();
        const u16* WH = mat ? nH : sH;
        const u16* WL = mat ? nL : sL;
        for (int idx = tid; idx < 2048; idx += 256) {
            int l = idx & 63;
            int q = idx >> 6;
            int hilo = q & 1;
            int ks = (q >> 1) & 1;
            int ct = q >> 2;
            int c = ct * 16 + (l & 15);
            int k = ks * 32 + (l >> 4) * 8;
            const u16* Wp = hilo ? WL : WH;
            bf16x8 wv_ = *reinterpret_cast<const bf16x8*>(Wp + (size_t)c * 64 + k);
            *reinterpret_cast<bf16x8*>(&Ws[idx * 8]) = wv_;
        }
        __syncthreads();
#pragma unroll
        for (int ct = 0; ct < 8; ++ct) {
#pragma unroll
            for (int ks = 0; ks < 2; ++ks) {
                int s = mat * 2 + ks;    // sat: x slices 0-1; nei: x slices 2-3
                int base = (ct * 2 + ks) * 1024;
                bf16x8 bh = *reinterpret_cast<const bf16x8*>(&Ws[base + lane * 8]);
                bf16x8 bl = *reinterpret_cast<const bf16x8*>(&Ws[base + 512 + lane * 8]);
                f32x4* ac = mat ? &accN[ct] : &accS[ct];
                *ac = __builtin_amdgcn_mfma_f32_16x16x32_bf16(axh[s], bh, *ac, 0, 0, 0);
                *ac = __builtin_amdgcn_mfma_f32_16x16x32_bf16(axh[s], bl, *ac, 0, 0, 0);
                *ac = __builtin_amdgcn_mfma_f32_16x16x32_bf16(axl[s], bh, *ac, 0, 0, 0);
            }
        }
    }

#pragma unroll
    for (int ct = 0; ct < 8; ++ct) {
        int c = ct * 16 + (lane & 15);
        float bs = satb[c], bn = neib[c];
#pragma unroll
        for (int r = 0; r < 4; ++r) {
            int row = r0 + (lane >> 4) * 4 + r;
            float v = fmaxf(accS[ct][r] + bs, 0.f) + 0.5f * fmaxf(accN[ct][r] + bn, 0.f);
            u16 h = f2bf(v);
            outH[(size_t)row * 128 + c] = h;
            outL[(size_t)row * 128 + c] = f2bf(v - bf2f(h));
        }
    }
}

// ---------------- wave-per-node softmax + aggregation ----------------
// 2 edge-rows per wave-op: lanes 0-31 handle even edge (float4 of dims),
// lanes 32-63 the odd edge. 8 pairs (16 edges) per unrolled body.
__global__ __launch_bounds__(256) void k_aggregate(
    const float* __restrict__ h, const float* __restrict__ as_,
    const float* __restrict__ ad_, const int* __restrict__ start,
    const int* __restrict__ deg, const int* __restrict__ csr_src,
    const float* __restrict__ bias, u16* __restrict__ outH, u16* __restrict__ outL)
{
    int wid = (blockIdx.x * 256 + threadIdx.x) >> 6;
    int lane = threadIdx.x & 63;
    if (wid >= N_NODES) return;

    const int s0 = start[wid];
    const int s1 = s0 + deg[wid];
    const float adi = ad_[wid];
    const int l32 = lane & 31;
    const bool hodd = lane >= 32;

    float4 acc = make_float4(0.f, 0.f, 0.f, 0.f);
    float ssum = 0.f;
    for (int base = s0; base < s1; base += 64) {
        int k = base + lane;
        int cnt = min(64, s1 - base);   // wave-uniform
        int jj = 0;
        float p = 0.f;
        if (k < s1) {
            jj = csr_src[k];
            float e = as_[jj] + adi;
            e = (e > 0.f) ? e : 0.2f * e;
            p = __expf(e);              // |e| << 88: no max-shift needed
            ssum += p;
        }
        for (int t = 0; t < cnt; t += 16) {   // 8 pairs; tail pairs carry p=0
            float pw[8];
            const float4* hp[8];
#pragma unroll
            for (int q = 0; q < 8; ++q) {
                int e0 = t + 2 * q;           // wave-uniform
                float plo = rdlane_f(p, e0), phi = rdlane_f(p, e0 + 1);
                int jlo = __builtin_amdgcn_readlane(jj, e0);
                int jhi = __builtin_amdgcn_readlane(jj, e0 + 1);
                pw[q] = hodd ? phi : plo;
                int j = hodd ? jhi : jlo;
                hp[q] = (const float4*)&h[(size_t)j * DIM + 4 * l32];
            }
            float4 hv[8];
#pragma unroll
            for (int q = 0; q < 8; ++q) hv[q] = *hp[q];
#pragma unroll
            for (int q = 0; q < 8; ++q) {
                acc.x = fmaf(pw[q], hv[q].x, acc.x);
                acc.y = fmaf(pw[q], hv[q].y, acc.y);
                acc.z = fmaf(pw[q], hv[q].z, acc.z);
                acc.w = fmaf(pw[q], hv[q].w, acc.w);
            }
        }
    }
#pragma unroll
    for (int off = 32; off; off >>= 1) ssum += __shfl_xor(ssum, off);
    acc.x += __shfl_xor(acc.x, 32);
    acc.y += __shfl_xor(acc.y, 32);
    acc.z += __shfl_xor(acc.z, 32);
    acc.w += __shfl_xor(acc.w, 32);
    float inv = 1.f / (ssum + 1e-16f);

    if (!hodd) {
        float4 bv = *(const float4*)&bias[4 * l32];
        float o0 = fmaxf(fmaf(acc.x, inv, bv.x), 0.f);
        float o1 = fmaxf(fmaf(acc.y, inv, bv.y), 0.f);
        float o2 = fmaxf(fmaf(acc.z, inv, bv.z), 0.f);
        float o3 = fmaxf(fmaf(acc.w, inv, bv.w), 0.f);
        u16 h0 = f2bf(o0), h1 = f2bf(o1), h2 = f2bf(o2), h3 = f2bf(o3);
        ushort4 hvv = make_ushort4(h0, h1, h2, h3);
        ushort4 lvv = make_ushort4(f2bf(o0 - bf2f(h0)), f2bf(o1 - bf2f(h1)),
                                   f2bf(o2 - bf2f(h2)), f2bf(o3 - bf2f(h3)));
        *(ushort4*)&outH[(size_t)wid * 128 + 4 * l32] = hvv;
        *(ushort4*)&outL[(size_t)wid * 128 + 4 * l32] = lvv;
    }
}

extern "C" void kernel_launch(void* const* d_in, const int* in_sizes, int n_in,
                              void* d_out, int out_size, void* d_ws, size_t ws_size,
                              hipStream_t stream) {
    (void)in_sizes; (void)n_in; (void)out_size; (void)ws_size;

    const float* x       = (const float*)d_in[0];
    const int*   ei      = (const int*)d_in[1];
    const float* sat_W   = (const float*)d_in[2];
    const float* sat_b   = (const float*)d_in[3];
    const float* neigh_W = (const float*)d_in[4];
    const float* neigh_b = (const float*)d_in[5];
    const float* c1_W    = (const float*)d_in[6];
    const float* c1_as   = (const float*)d_in[7];
    const float* c1_ad   = (const float*)d_in[8];
    const float* c1_b    = (const float*)d_in[9];
    const float* c2_W    = (const float*)d_in[10];
    const float* c2_as   = (const float*)d_in[11];
    const float* c2_ad   = (const float*)d_in[12];
    const float* c2_b    = (const float*)d_in[13];
    const float* fc1_W   = (const float*)d_in[14];
    const float* fc1_b   = (const float*)d_in[15];
    const float* fc2_W   = (const float*)d_in[16];
    const float* fc2_b   = (const float*)d_in[17];

    const int* e_src = ei;
    const int* e_dst = ei + N_EDGES;

    char* w = (char*)d_ws;
    float* hB     = (float*)(w);                  // [N,128] f32
    u16*   xH     = (u16*)  (w + 20480000);
    u16*   xL     = (u16*)  (w + 30720000);
    u16*   hH     = (u16*)  (w + 40960000);
    u16*   hL     = (u16*)  (w + 51200000);
    float* as_    = (float*)(w + 61440000);
    float* ad_    = (float*)(w + 61600000);
    int*   deg    = (int*)  (w + 61760000);
    int*   start  = (int*)  (w + 61920000);
    int*   cursor = (int*)  (w + 62080000);
    int*   counter= (int*)  (w + 62240000);
    int*   csr    = (int*)  (w + 62240256);
    u16*   wa     = (u16*)  (w + 64960512);

    u16 *satH = wa,          *satL = wa + 8192;
    u16 *neiH = wa + 16384,  *neiL = wa + 24576;
    u16 *c1H  = wa + 32768,  *c1L  = wa + 49152;
    u16 *c2H  = wa + 65536,  *c2L  = wa + 81920;
    u16 *f1H  = wa + 98304,  *f1L  = wa + 114688;
    u16 *f2H  = wa + 131072, *f2L  = wa + 139264;

    dim3 b(256);
    k_wcvt<<<dim3(64, 6), b, 0, stream>>>(sat_W, neigh_W, c1_W, c2_W, fc1_W, fc2_W, wa);
    k_xcvt<<<5000, b, 0, stream>>>(x, xH, xL, deg, counter);

    k_deg_count <<<2500, b, 0, stream>>>(e_dst, deg);
    k_assign    <<<157,  b, 0, stream>>>(deg, counter, start, cursor, csr);
    k_fill_edges<<<2500, b, 0, stream>>>(e_src, e_dst, cursor, csr);

    k_encoder<<<625, b, 0, stream>>>(xH, xL, satH, satL, neiH, neiL, sat_b, neigh_b, hH, hL);

    k_mfma_gemm<8, true, EPI_F32RAW><<<625, b, 0, stream>>>(
        hH, hL, c1H, c1L, nullptr, 128, hB, 128, nullptr, nullptr,
        c1_as, c1_ad, as_, ad_);
    k_aggregate<<<10000, b, 0, stream>>>(hB, as_, ad_, start, deg, csr, c1_b, hH, hL);

    k_mfma_gemm<8, true, EPI_F32RAW><<<625, b, 0, stream>>>(
        hH, hL, c2H, c2L, nullptr, 128, hB, 128, nullptr, nullptr,
        c2_as, c2_ad, as_, ad_);
    k_aggregate<<<10000, b, 0, stream>>>(hB, as_, ad_, start, deg, csr, c2_b, hH, hL);

    k_mfma_gemm<8, false, EPI_RELU_BF16><<<625, b, 0, stream>>>(
        hH, hL, f1H, f1L, fc1_b, 128, nullptr, 0, xH, xL,
        nullptr, nullptr, nullptr, nullptr);
    k_mfma_gemm<4, false, EPI_BIAS_F32><<<625, b, 0, stream>>>(
        xH, xL, f2H, f2L, fc2_b, 54, (float*)d_out, 54, nullptr, nullptr,
        nullptr, nullptr, nullptr, nullptr);
}